// Round 1
// baseline (427.232 us; speedup 1.0000x reference)
//
#include <hip/hip_runtime.h>

namespace {
constexpr int S_LEN = 512;
constexpr int BATCH = 1024;
constexpr int TAG = 64;
constexpr int START_IDX = 0;
constexpr int END_IDX = 1;
constexpr float NEG_INF = -10000.0f;
constexpr int PD = 8;  // prefetch depth (steps ahead)
constexpr float LN2F = 0.69314718055994530942f;

typedef float v2f __attribute__((ext_vector_type(2)));
typedef float v4f __attribute__((ext_vector_type(4)));
}

// One wave (64 lanes) per batch; lane = destination tag j.
// Linear-domain recurrence: p_j holds exp(alpha_j - M), M = etot*ln2 tracked as an
// integer power-of-2 count. Per step:
//   t_j  = sum_i E[j,i] * p_i          (LDS broadcast round-trip + FMA tree)
//   p_j' = t_j * exp(feat_s_j) * 2^-e  (exp(feat) and 2^-e are OFF the serial chain)
// e = exponent of previous step's anchor p (lane 2) -> exact renormalization,
// no exp/log/readlane on the critical path.
__global__ __launch_bounds__(64, 1) void crf_fwd_kernel(
    const float* __restrict__ feats,   // [S, B, T]
    const float* __restrict__ mask,    // [S, B]
    const float* __restrict__ trans,   // [T, T]
    float* __restrict__ out) {         // [B]
  const int b = blockIdx.x;
  const int lane = threadIdx.x;  // tag j

  __shared__ __align__(16) float p_lds[TAG];

  // ---- one-time: E row j into registers (exp of transition row), 32 v2f ----
  v2f E[TAG / 2];
  {
    const float* row = trans + lane * TAG;
#pragma unroll
    for (int k = 0; k < TAG / 4; ++k) {
      v4f tv;
      __builtin_memcpy(&tv, row + 4 * k, sizeof(v4f));
      E[2 * k]     = v2f{__expf(tv.x), __expf(tv.y)};  // exp(-10000) -> 0, no NaN
      E[2 * k + 1] = v2f{__expf(tv.z), __expf(tv.w)};
    }
  }

  // p = exp(alpha0 - 0): 1 at START, 0 elsewhere
  float p = (lane == START_IDX) ? 1.0f : 0.0f;
  int etot = 0;  // running power-of-2 count: M = etot * ln2 (exact scaling)

  const float* fptr = feats + (size_t)b * TAG + lane;
  const float* mptr = mask + b;

  // ---- prefetch ring: feat[s,b,lane] is ONE float per lane per step ----
  float fbuf[PD], mbuf[PD];
#pragma unroll
  for (int d = 0; d < PD; ++d) {
    fbuf[d] = fptr[(size_t)d * (BATCH * TAG)];
    mbuf[d] = mptr[(size_t)d * BATCH];
  }

  p_lds[lane] = p;
  __builtin_amdgcn_wave_barrier();

  for (int sb = 0; sb < S_LEN; sb += PD) {
#pragma unroll
    for (int d = 0; d < PD; ++d) {
      const float fcur = fbuf[d];
      const float mcur = mbuf[d];
      // mask = (s < lens[b]) is monotone non-increasing in s -> safe to stop.
      if (mcur == 0.0f) goto fin;

      int sp = sb + d + PD;
      sp = (sp < S_LEN) ? sp : (S_LEN - 1);  // clamp: harmless re-read of last row
      fbuf[d] = fptr[(size_t)sp * (BATCH * TAG)];
      mbuf[d] = mptr[(size_t)sp * BATCH];

      // ---- OFF critical path (overlaps the LDS round-trip below) ----
      // exponent of previous step's anchor p (lane 2; >0 for all steps >= 1,
      // ==0 only before step 1 where we force scale = 1)
      const unsigned pb = __builtin_amdgcn_readlane(__float_as_uint(p), 2);
      const unsigned eb = (pb == 0u) ? 127u : (pb >> 23);
      etot += (int)eb - 127;
      const float scale = __uint_as_float((254u - eb) << 23);  // 2^(127-eb), exact
      const float cg = __expf(fcur) * scale;

      // ---- critical path: t_j = sum_i E[j,i] * p_i ----
      // broadcast b128 reads (all lanes same addr): conflict-free
      v2f acc0 = {0.f, 0.f}, acc1 = {0.f, 0.f}, acc2 = {0.f, 0.f}, acc3 = {0.f, 0.f};
      v2f acc4 = {0.f, 0.f}, acc5 = {0.f, 0.f}, acc6 = {0.f, 0.f}, acc7 = {0.f, 0.f};
#pragma unroll
      for (int k = 0; k < 4; ++k) {
        v4f q0, q1, q2, q3;
        __builtin_memcpy(&q0, p_lds + 16 * k + 0,  sizeof(v4f));
        __builtin_memcpy(&q1, p_lds + 16 * k + 4,  sizeof(v4f));
        __builtin_memcpy(&q2, p_lds + 16 * k + 8,  sizeof(v4f));
        __builtin_memcpy(&q3, p_lds + 16 * k + 12, sizeof(v4f));
        acc0 += v2f{q0.x, q0.y} * E[8 * k + 0];  // -> v_pk_fma_f32
        acc1 += v2f{q0.z, q0.w} * E[8 * k + 1];
        acc2 += v2f{q1.x, q1.y} * E[8 * k + 2];
        acc3 += v2f{q1.z, q1.w} * E[8 * k + 3];
        acc4 += v2f{q2.x, q2.y} * E[8 * k + 4];
        acc5 += v2f{q2.z, q2.w} * E[8 * k + 5];
        acc6 += v2f{q3.x, q3.y} * E[8 * k + 6];
        acc7 += v2f{q3.z, q3.w} * E[8 * k + 7];
      }
      const v2f s0 = (acc0 + acc1) + (acc2 + acc3);
      const v2f s1 = (acc4 + acc5) + (acc6 + acc7);
      const v2f st = s0 + s1;
      const float t = st.x + st.y;  // t >= 0; t==0 only for tag 0 (E row 0 is zero)

      p = t * cg;  // single on-chain multiply replaces exp+log+readlane

      __builtin_amdgcn_wave_barrier();  // WAR: write below stays after reads above
      p_lds[lane] = p;
      __builtin_amdgcn_wave_barrier();  // RAW: next iter's reads after this write
    }
  }
fin:
  // ---- epilogue: out[b] = logsumexp_j(M + log p_j + trans[END, j]) ----
  {
    const float a = (float)etot * LN2F + __logf(p) + trans[END_IDX * TAG + lane];
    float mx = a;  // p==0 -> a=-inf; lane 2 always finite so mx finite
#pragma unroll
    for (int off = 32; off >= 1; off >>= 1) mx = fmaxf(mx, __shfl_xor(mx, off, 64));
    float e = __expf(a - mx);
#pragma unroll
    for (int off = 32; off >= 1; off >>= 1) e += __shfl_xor(e, off, 64);
    if (lane == 0) out[b] = mx + __logf(e);
  }
}

extern "C" void kernel_launch(void* const* d_in, const int* in_sizes, int n_in,
                              void* d_out, int out_size, void* d_ws, size_t ws_size,
                              hipStream_t stream) {
  const float* feats = (const float*)d_in[0];
  const float* mask = (const float*)d_in[1];
  const float* trans = (const float*)d_in[2];
  float* out = (float*)d_out;
  crf_fwd_kernel<<<dim3(BATCH), dim3(64), 0, stream>>>(feats, mask, trans, out);
}

// Round 2
// 258.027 us; speedup vs baseline: 1.6558x; 1.6558x over previous
//
#include <hip/hip_runtime.h>

namespace {
constexpr int S_LEN = 512;
constexpr int BATCH = 1024;
constexpr int TAG = 64;
constexpr int START_IDX = 0;
constexpr int END_IDX = 1;
constexpr float NEG_INF = -10000.0f;
constexpr int CHUNK = 64;              // steps per LDS chunk (16 KB)
constexpr float LN2F = 0.69314718055994530942f;

typedef float v2f __attribute__((ext_vector_type(2)));
typedef float v4f __attribute__((ext_vector_type(4)));

typedef const __attribute__((address_space(1))) void* gas_ptr;
typedef __attribute__((address_space(3))) void* las_ptr;

__device__ inline void gld_lds16(const float* g, float* l) {
  // LDS dest = wave-uniform base + lane*16 (hardware); global src is per-lane.
  __builtin_amdgcn_global_load_lds((gas_ptr)(const void*)g, (las_ptr)(void*)l, 16, 0, 0);
}
}

// One wave (64 lanes) per batch; lane = destination tag j.
// Linear-domain recurrence: p_j = exp(alpha_j - etot*ln2), renormalized each step by
// an exact power of 2 taken from the exponent bits of lane 2's p (off-chain readlane).
//   t_j  = sum_i E[j,i] * p_i      (LDS broadcast round-trip + FMA tree)
//   p_j' = t_j * exp(feat) * 2^-e  (exp(feat) from LDS-staged feats, off-chain)
// Global memory never appears in the per-step chain: feats are staged 64 steps ahead
// into double-buffered LDS via global_load_lds; mask is collapsed to L = sum(mask)
// once at entry (mask is monotone in s).
__global__ __launch_bounds__(64, 1) void crf_fwd_kernel(
    const float* __restrict__ feats,   // [S, B, T]
    const float* __restrict__ mask,    // [S, B]
    const float* __restrict__ trans,   // [T, T]
    float* __restrict__ out) {         // [B]
  const int b = blockIdx.x;
  const int lane = threadIdx.x;  // tag j

  __shared__ __align__(16) float fchunk[2][CHUNK * TAG];  // 2 x 16 KB
  __shared__ __align__(16) float p_lds[TAG];

  // ---- effective length L = sum_s mask[s,b] (mask monotone non-increasing) ----
  int L;
  {
    float sum = 0.0f;
#pragma unroll
    for (int k = 0; k < S_LEN / 64; ++k) sum += mask[(size_t)(lane + 64 * k) * BATCH + b];
#pragma unroll
    for (int off = 32; off >= 1; off >>= 1) sum += __shfl_xor(sum, off, 64);
    L = (int)(sum + 0.5f);
  }

  // ---- one-time: E row j into registers (exp of transition row), 32 v2f ----
  v2f E[TAG / 2];
  {
    const float* row = trans + lane * TAG;
#pragma unroll
    for (int k = 0; k < TAG / 4; ++k) {
      v4f tv;
      __builtin_memcpy(&tv, row + 4 * k, sizeof(v4f));
      E[2 * k]     = v2f{__expf(tv.x), __expf(tv.y)};  // exp(-10000) -> 0, no NaN
      E[2 * k + 1] = v2f{__expf(tv.z), __expf(tv.w)};
    }
  }

  // per-lane invariant pieces of the staging address:
  // one gld_lds16 instruction moves 4 rows (4 x 256 B): lane l -> row l>>4, col (l&15)*4
  const float* gstage0 =
      feats + ((size_t)(lane >> 4) * BATCH + b) * TAG + ((lane & 15) << 2);

  auto stage_chunk = [&](int base_s, int nb) {
    const float* g0 = gstage0 + (size_t)base_s * (BATCH * TAG);
#pragma unroll
    for (int q = 0; q < 16; ++q) {
      gld_lds16(g0 + (size_t)(4 * q) * (BATCH * TAG), &fchunk[nb][q * 256]);
    }
  };

  float p = (lane == START_IDX) ? 1.0f : 0.0f;
  int etot = 0;  // running power-of-2 count: M = etot * ln2 (exact scaling)

  p_lds[lane] = p;
  __builtin_amdgcn_wave_barrier();

  // ---- prologue: stage chunk 0 and wait for it ----
  stage_chunk(0, 0);
  asm volatile("s_waitcnt vmcnt(0)" ::: "memory");
  __builtin_amdgcn_sched_barrier(0);
  __builtin_amdgcn_wave_barrier();

  for (int c = 0;; ++c) {
    const int base = c * CHUNK;
    int n = L - base;
    if (n <= 0) break;
    if (n > CHUNK) n = CHUNK;

    const int nbase = base + CHUNK;
    if (nbase < S_LEN) stage_chunk(nbase, (c + 1) & 1);  // async, 64 steps ahead

    const float* fb = &fchunk[c & 1][0];

    auto step = [&](int i) {
      const float fcur = fb[i * TAG + lane];  // ds_read_b32, lane-striped (conflict-free)

      // ---- off critical path (overlaps the LDS round-trip below) ----
      const unsigned pb = __builtin_amdgcn_readlane(__float_as_uint(p), 2);
      const unsigned eb = (pb == 0u) ? 127u : (pb >> 23);
      etot += (int)eb - 127;
      const float scale = __uint_as_float((254u - eb) << 23);  // 2^(127-eb), exact
      const float cg = __expf(fcur) * scale;

      // ---- critical path: t_j = sum_i E[j,i] * p_i (broadcast b128 reads) ----
      v2f acc0 = {0.f, 0.f}, acc1 = {0.f, 0.f}, acc2 = {0.f, 0.f}, acc3 = {0.f, 0.f};
      v2f acc4 = {0.f, 0.f}, acc5 = {0.f, 0.f}, acc6 = {0.f, 0.f}, acc7 = {0.f, 0.f};
#pragma unroll
      for (int k = 0; k < 4; ++k) {
        v4f q0, q1, q2, q3;
        __builtin_memcpy(&q0, p_lds + 16 * k + 0,  sizeof(v4f));
        __builtin_memcpy(&q1, p_lds + 16 * k + 4,  sizeof(v4f));
        __builtin_memcpy(&q2, p_lds + 16 * k + 8,  sizeof(v4f));
        __builtin_memcpy(&q3, p_lds + 16 * k + 12, sizeof(v4f));
        acc0 += v2f{q0.x, q0.y} * E[8 * k + 0];  // -> v_pk_fma_f32
        acc1 += v2f{q0.z, q0.w} * E[8 * k + 1];
        acc2 += v2f{q1.x, q1.y} * E[8 * k + 2];
        acc3 += v2f{q1.z, q1.w} * E[8 * k + 3];
        acc4 += v2f{q2.x, q2.y} * E[8 * k + 4];
        acc5 += v2f{q2.z, q2.w} * E[8 * k + 5];
        acc6 += v2f{q3.x, q3.y} * E[8 * k + 6];
        acc7 += v2f{q3.z, q3.w} * E[8 * k + 7];
      }
      const v2f s0 = (acc0 + acc1) + (acc2 + acc3);
      const v2f s1 = (acc4 + acc5) + (acc6 + acc7);
      const v2f st = s0 + s1;
      const float t = st.x + st.y;

      p = t * cg;  // single on-chain multiply

      __builtin_amdgcn_wave_barrier();  // WAR: write below stays after reads above
      p_lds[lane] = p;
      __builtin_amdgcn_wave_barrier();  // RAW: next step's reads after this write
    };

    if (n == CHUNK) {
#pragma unroll 8
      for (int i = 0; i < CHUNK; ++i) step(i);
    } else {
      for (int i = 0; i < n; ++i) step(i);
      break;  // L reached inside this chunk
    }

    if (nbase >= L) break;  // done; skip the drain

    // next chunk's loads were issued 64 steps (~16k cycles) ago: drain is ~free
    asm volatile("s_waitcnt vmcnt(0)" ::: "memory");
    __builtin_amdgcn_sched_barrier(0);
    __builtin_amdgcn_wave_barrier();
  }

  // drain any in-flight staging before LDS is deallocated at wave exit
  asm volatile("s_waitcnt vmcnt(0)" ::: "memory");

  // ---- epilogue: out[b] = logsumexp_j(etot*ln2 + log p_j + trans[END, j]) ----
  {
    const float a = (float)etot * LN2F + __logf(p) + trans[END_IDX * TAG + lane];
    float mx = a;  // p==0 -> a=-inf; lane 2 always finite so mx finite
#pragma unroll
    for (int off = 32; off >= 1; off >>= 1) mx = fmaxf(mx, __shfl_xor(mx, off, 64));
    float e = __expf(a - mx);
#pragma unroll
    for (int off = 32; off >= 1; off >>= 1) e += __shfl_xor(e, off, 64);
    if (lane == 0) out[b] = mx + __logf(e);
  }
}

extern "C" void kernel_launch(void* const* d_in, const int* in_sizes, int n_in,
                              void* d_out, int out_size, void* d_ws, size_t ws_size,
                              hipStream_t stream) {
  const float* feats = (const float*)d_in[0];
  const float* mask = (const float*)d_in[1];
  const float* trans = (const float*)d_in[2];
  float* out = (float*)d_out;
  crf_fwd_kernel<<<dim3(BATCH), dim3(64), 0, stream>>>(feats, mask, trans, out);
}